// Round 6
// baseline (96.465 us; speedup 1.0000x reference)
//
#include <hip/hip_runtime.h>

#define B_  16
#define LC  2048
#define LQ  512
#define DD  128
#define L2E 1.44269504088896340736f
#define SP  16

typedef __attribute__((ext_vector_type(8))) short bf16x8;
typedef __attribute__((ext_vector_type(4))) float f32x4;
typedef unsigned short u16;
typedef unsigned int   u32;

#define MFMA(a,b,c) __builtin_amdgcn_mfma_f32_16x16x32_bf16((a),(b),(c),0,0,0)

__device__ __forceinline__ u16 f2bf(float x){
  u32 u = __builtin_bit_cast(u32, x);
  u32 r = (u + 0x7FFFu + ((u >> 16) & 1u)) >> 16;
  return (u16)r;
}
__device__ __forceinline__ float bf2f(u16 h){
  u32 u = ((u32)h) << 16;
  return __builtin_bit_cast(float, u);
}
__device__ __forceinline__ bf16x8 ldb8(const u16* p){
  return *reinterpret_cast<const bf16x8*>(p);
}
// swizzled LDS read addr for a [rows][256B] tile: byte ^= (row&7)<<4
__device__ __forceinline__ const u16* swz(const u16* base, int row, int colb){
  return base + (row << 7) + ((colb ^ ((row & 7) << 4)) >> 1);
}
#define GLOAD_LDS(g, l) \
  __builtin_amdgcn_global_load_lds((const __attribute__((address_space(1))) void*)(g), \
                                   (__attribute__((address_space(3))) void*)(l), 16, 0, 0)

// ---------------- K0: bf16 staging + transposes + row-dots ----------------
// blocks 0..511: C tiles -> Cb (plain bf16 rows), CbT, sub0
// blocks 512..639: Q tiles -> Qwb (w4mlu-scaled rows), QbT (plain), sub1
__global__ void prep(const float* __restrict__ C, const float* __restrict__ Q,
                     const float* __restrict__ w4C, const float* __restrict__ w4Q,
                     const float* __restrict__ w4mlu,
                     u16* __restrict__ Cb,  u16* __restrict__ CbT,
                     u16* __restrict__ Qwb, u16* __restrict__ QbT,
                     float* __restrict__ sub0, float* __restrict__ sub1){
  __shared__ u16 tile[64][130];
  __shared__ float wl[128];
  int t = threadIdx.x, blk = blockIdx.x;
  int lane = t & 63;
  bool isC = blk < 512;
  if (t < 128) wl[t] = w4mlu[t];
  __syncthreads();
  float2 wv = reinterpret_cast<const float2*>(isC ? w4C : w4Q)[lane];
  if (isC) {
    int b = blk >> 5, ct = blk & 31, c0 = ct << 6;
    const float* src = C + ((size_t)(b*LC + c0))*DD;
    for (int k = 0; k < 16; ++k) {
      int idx = t + (k << 8);
      int r = idx >> 6, d2 = idx & 63;
      float2 v = reinterpret_cast<const float2*>(src + (size_t)r*DD)[d2];
      float sdot = v.x*wv.x + v.y*wv.y;
      #pragma unroll
      for (int o = 32; o > 0; o >>= 1) sdot += __shfl_xor(sdot, o);
      if (lane == 0) sub0[b*LC + c0 + r] = sdot;
      u16 h0 = f2bf(v.x), h1 = f2bf(v.y);
      size_t o = ((size_t)(b*LC + c0 + r))*DD + 2*d2;
      *reinterpret_cast<u32*>(Cb + o) = (u32)h0 | ((u32)h1 << 16);
      tile[r][2*d2]   = h0;
      tile[r][2*d2+1] = h1;
    }
    __syncthreads();
    for (int k = 0; k < 8; ++k) {
      int ch = t + (k << 8);
      int d = ch >> 4, c4 = (ch & 15) << 2;
      u32 lo = (u32)tile[c4][d]   | ((u32)tile[c4+1][d] << 16);
      u32 hi = (u32)tile[c4+2][d] | ((u32)tile[c4+3][d] << 16);
      uint2 u; u.x = lo; u.y = hi;
      *reinterpret_cast<uint2*>(CbT + ((size_t)(b*DD + d))*LC + c0 + c4) = u;
    }
  } else {
    int bq = blk - 512;
    int b = bq >> 3, qt = bq & 7, q0 = qt << 6;
    const float* src = Q + ((size_t)(b*LQ + q0))*DD;
    for (int k = 0; k < 16; ++k) {
      int idx = t + (k << 8);
      int r = idx >> 6, d2 = idx & 63;
      float2 v = reinterpret_cast<const float2*>(src + (size_t)r*DD)[d2];
      float sdot = v.x*wv.x + v.y*wv.y;
      #pragma unroll
      for (int o = 32; o > 0; o >>= 1) sdot += __shfl_xor(sdot, o);
      if (lane == 0) sub1[b*LQ + q0 + r] = sdot;
      float qw0 = v.x * wl[2*d2], qw1 = v.y * wl[2*d2+1];
      size_t o = ((size_t)(b*LQ + q0 + r))*DD + 2*d2;
      *reinterpret_cast<u32*>(Qwb + o) = (u32)f2bf(qw0) | ((u32)f2bf(qw1) << 16);
      tile[r][2*d2]   = f2bf(v.x);
      tile[r][2*d2+1] = f2bf(v.y);
    }
    __syncthreads();
    for (int k = 0; k < 8; ++k) {
      int ch = t + (k << 8);
      int d = ch >> 4, c4 = (ch & 15) << 2;
      u32 lo = (u32)tile[c4][d]   | ((u32)tile[c4+1][d] << 16);
      u32 hi = (u32)tile[c4+2][d] | ((u32)tile[c4+3][d] << 16);
      uint2 u; u.x = lo; u.y = hi;
      *reinterpret_cast<uint2*>(QbT + ((size_t)(b*DD + d))*LQ + q0 + c4) = u;
    }
  }
}

// ---------------- K1: flash column-softmax -> partial T ----------------
// grid 2048 = 16 b x 8 qblk(64) x 16 csplit(128). S = Qw·C^T + sub0.
__global__ __launch_bounds__(256, 3)
void flashT(const u16* __restrict__ Qwb, const u16* __restrict__ Cb,
            const u16* __restrict__ CbT, const float* __restrict__ sub0,
            float* __restrict__ mPart, float* __restrict__ lPart,
            u16* __restrict__ TaccP){
  __shared__ __align__(16) u16 buf[128*128];
  __shared__ u16 Pl[64][136];
  int bid = blockIdx.x;
  int id = (bid & 7) * 256 + (bid >> 3);
  int b = id >> 7, qb = (id >> 4) & 7, sp = id & 15;
  int c0 = sp * 128;
  int w = threadIdx.x >> 6, l = threadIdx.x & 63;
  int lj = l & 15, lg = l >> 4;

  {
    const char* gb = (const char*)(Cb + ((size_t)(b*LC + c0))*DD);
    #pragma unroll
    for (int i = 0; i < 8; ++i) {
      int off = (w*8 + i)*1024 + l*16;
      int row = off >> 8, col = off & 255;
      int src = (row << 8) | (col ^ ((row & 7) << 4));
      GLOAD_LDS(gb + src, (char*)buf + off);
    }
  }
  const u16* Qrow = Qwb + ((size_t)(b*LQ + qb*64 + w*16 + lj))*DD;
  bf16x8 aq[4];
  #pragma unroll
  for (int k = 0; k < 4; ++k) aq[k] = ldb8(Qrow + k*32 + lg*8);
  float s0v[8];
  #pragma unroll
  for (int f = 0; f < 8; ++f) s0v[f] = sub0[b*LC + c0 + f*16 + lj];
  __syncthreads();

  f32x4 s[8];
  #pragma unroll
  for (int f = 0; f < 8; ++f) s[f] = (f32x4){0.f,0.f,0.f,0.f};
  #pragma unroll
  for (int ks = 0; ks < 4; ++ks) {
    #pragma unroll
    for (int f = 0; f < 8; ++f)
      s[f] = MFMA(aq[ks], ldb8(swz(buf, f*16 + lj, ks*64 + lg*16)), s[f]);
  }
  __syncthreads();

  {
    const char* gb = (const char*)CbT + ((size_t)b*DD)*LC*2 + (size_t)c0*2;
    #pragma unroll
    for (int i = 0; i < 8; ++i) {
      int off = (w*8 + i)*1024 + l*16;
      int row = off >> 8, col = off & 255;
      size_t src = (size_t)row*(LC*2) + (col ^ ((row & 7) << 4));
      GLOAD_LDS(gb + src, (char*)buf + off);
    }
  }

  float tm[4] = {-1e30f,-1e30f,-1e30f,-1e30f};
  #pragma unroll
  for (int f = 0; f < 8; ++f) {
    #pragma unroll
    for (int r = 0; r < 4; ++r) { s[f][r] += s0v[f]; tm[r] = fmaxf(tm[r], s[f][r]); }
  }
  #pragma unroll
  for (int r = 0; r < 4; ++r) {
    #pragma unroll
    for (int m = 1; m < 16; m <<= 1) tm[r] = fmaxf(tm[r], __shfl_xor(tm[r], m));
  }
  float psum[4] = {0.f,0.f,0.f,0.f};
  #pragma unroll
  for (int f = 0; f < 8; ++f) {
    #pragma unroll
    for (int r = 0; r < 4; ++r) {
      float p = exp2f((s[f][r] - tm[r]) * L2E);
      psum[r] += p;
      Pl[w*16 + lg*4 + r][f*16 + lj] = f2bf(p);
    }
  }
  #pragma unroll
  for (int r = 0; r < 4; ++r) {
    #pragma unroll
    for (int m = 1; m < 16; m <<= 1) psum[r] += __shfl_xor(psum[r], m);
  }
  int pbase = (b*8 + qb)*SP + sp;
  if (lj == 0) {
    #pragma unroll
    for (int r = 0; r < 4; ++r) {
      mPart[pbase*64 + w*16 + lg*4 + r] = tm[r];
      lPart[pbase*64 + w*16 + lg*4 + r] = psum[r];
    }
  }
  __syncthreads();

  f32x4 tacc[8];
  #pragma unroll
  for (int f = 0; f < 8; ++f) tacc[f] = (f32x4){0.f,0.f,0.f,0.f};
  #pragma unroll
  for (int ks = 0; ks < 4; ++ks) {
    bf16x8 ap = *reinterpret_cast<const bf16x8*>(&Pl[w*16 + lj][ks*32 + lg*8]);
    #pragma unroll
    for (int f = 0; f < 8; ++f)
      tacc[f] = MFMA(ap, ldb8(swz(buf, f*16 + lj, ks*64 + lg*16)), tacc[f]);
  }
  #pragma unroll
  for (int f = 0; f < 8; ++f) {
    ushort4 hv;
    hv.x = f2bf(tacc[f][0]); hv.y = f2bf(tacc[f][1]);
    hv.z = f2bf(tacc[f][2]); hv.w = f2bf(tacc[f][3]);
    *reinterpret_cast<ushort4*>(TaccP + (((size_t)pbase*4 + w)*8 + f)*256 + lj*16 + lg*4) = hv;
  }
}

// ---------------- K1b: combine c-split partials -> TbT ----------------
__global__ void combineT(const float* __restrict__ mPart, const float* __restrict__ lPart,
                         const u16* __restrict__ TaccP, u16* __restrict__ TbT){
  __shared__ float fac[SP][64];
  __shared__ u16 Tt[64][68];
  int blk = blockIdx.x;
  int b = blk >> 4, qb = (blk >> 1) & 7, dh = blk & 1;
  int t = threadIdx.x;
  int base = (b*8 + qb)*SP;
  if (t < 64) {
    float m_[SP], mm = -1e30f;
    #pragma unroll
    for (int p = 0; p < SP; ++p) { m_[p] = mPart[(base+p)*64 + t]; mm = fmaxf(mm, m_[p]); }
    float lt = 0.f, e[SP];
    #pragma unroll
    for (int p = 0; p < SP; ++p) {
      e[p] = exp2f((m_[p] - mm) * L2E);
      lt += lPart[(base+p)*64 + t] * e[p];
    }
    float il = 1.0f / lt;
    #pragma unroll
    for (int p = 0; p < SP; ++p) fac[p][t] = e[p] * il;
  }
  __syncthreads();
  int lj = t >> 4, lg = (t >> 2) & 3, r = t & 3;
  for (int w = 0; w < 4; ++w) {
    int q = w*16 + lg*4 + r;
    for (int fi = 0; fi < 4; ++fi) {
      int f = dh*4 + fi;
      float acc = 0.f;
      #pragma unroll
      for (int p = 0; p < SP; ++p)
        acc += bf2f(TaccP[(((size_t)(base+p)*4 + w)*8 + f)*256 + t]) * fac[p][q];
      Tt[q][fi*16 + lj] = f2bf(acc);
    }
  }
  __syncthreads();
  for (int k = 0; k < 4; ++k) {
    int ch = t + (k << 8); int dl = ch >> 4, q4 = (ch & 15) << 2;
    u32 lo = (u32)Tt[q4][dl]   | ((u32)Tt[q4+1][dl] << 16);
    u32 hi = (u32)Tt[q4+2][dl] | ((u32)Tt[q4+3][dl] << 16);
    uint2 u; u.x = lo; u.y = hi;
    *reinterpret_cast<uint2*>(TbT + ((size_t)(b*DD + dh*64 + dl))*LQ + qb*64 + q4) = u;
  }
}

// ---------------- K2a: row-softmax + A-GEMM + P1 store (segs 0..2) --------
// grid 1024 = 16 b x 64 ctiles(32 c). 4 waves (256 thr), wave = q-frag mf.
// Swapped QK: A = Qw rows (staged chunks), B = Cb rows (resident). D[q][c].
__global__ __launch_bounds__(256, 2)
void rowsm_A(const float* __restrict__ Cf, const u16* __restrict__ Cb,
             const u16* __restrict__ Qwb, const u16* __restrict__ QbT,
             const float* __restrict__ sub1, u16* __restrict__ P1,
             float* __restrict__ out){
  __shared__ __align__(16) char smem[76800];
  u16*  cbl  = (u16*)smem;                 // [32 c][256B] swz, 8 KB
  char* stg0 = smem + 8192;                // 16 KB chunk buffer A
  char* stg1 = smem + 24576;               // 16 KB chunk buffer B
  u16*  Plq  = (u16*)(smem + 40960);       // [32 c][1024B] swz, 32 KB
  float* s1l = (float*)(smem + 73728);     // 512 f32
  float* redM = (float*)(smem + 75776);    // [4][32]
  float* redS = (float*)(smem + 76288);    // [4][32]

  int bid = blockIdx.x;
  int id = (bid & 7) * 128 + (bid >> 3);   // XCD swizzle, nwg=1024
  int b = id >> 6, ct = id & 63, c0 = ct * 32;
  int tid = threadIdx.x;
  int w = tid >> 6, l = tid & 63;
  int lj = l & 15, lg = l >> 4;

  // stage Cb tile [32][256B]
  {
    const char* gb = (const char*)(Cb + ((size_t)(b*LC + c0))*DD);
    #pragma unroll
    for (int i = 0; i < 2; ++i) {
      int off = i*4096 + tid*16;
      int row = off >> 8, col = off & 255;
      GLOAD_LDS(gb + ((row << 8) | (col ^ ((row & 7) << 4))), smem + off);
    }
  }
  // stage Qw chunk 0 -> stg0
  {
    const char* gb = (const char*)(Qwb + ((size_t)(b*LQ))*DD);
    #pragma unroll
    for (int i = 0; i < 4; ++i) {
      int off = i*4096 + tid*16;
      int row = off >> 8, col = off & 255;
      GLOAD_LDS(gb + ((row << 8) | (col ^ ((row & 7) << 4))), stg0 + off);
    }
  }
  if (tid < 128) ((float4*)s1l)[tid] = ((const float4*)(sub1 + b*LQ))[tid];
  __syncthreads();

  // hoist Cb B-fragments: B[k=d][col=c]
  bf16x8 ca[2][4];
  #pragma unroll
  for (int cf = 0; cf < 2; ++cf) {
    int row = cf*16 + lj;
    #pragma unroll
    for (int ks = 0; ks < 4; ++ks)
      ca[cf][ks] = ldb8(cbl + (row << 7) + (((ks*64 + lg*16) ^ ((row & 7) << 4)) >> 1));
  }

  // ---- phase I: S^T chunks. D[row=q][col=c]; wave w = q-subfrag of each chunk.
  f32x4 s[8][2];
  #pragma unroll
  for (int ch = 0; ch < 8; ++ch)
    #pragma unroll
    for (int cf = 0; cf < 2; ++cf) s[ch][cf] = (f32x4){0.f,0.f,0.f,0.f};

  #pragma unroll
  for (int ch = 0; ch < 8; ++ch) {
    if (ch < 7) {
      const char* gb = (const char*)(Qwb + ((size_t)(b*LQ + (ch+1)*64))*DD);
      char* db = (ch & 1) ? stg0 : stg1;
      #pragma unroll
      for (int i = 0; i < 4; ++i) {
        int off = i*4096 + tid*16;
        int row = off >> 8, col = off & 255;
        GLOAD_LDS(gb + ((row << 8) | (col ^ ((row & 7) << 4))), db + off);
      }
    }
    if (ch == 7) {   // early: QbT chunk 0 -> stg0 (free since ch==6 barrier)
      const char* gq = (const char*)QbT + ((size_t)b*DD)*LQ*2;
      #pragma unroll
      for (int i = 0; i < 4; ++i) {
        int off = i*4096 + tid*16;
        int row = off >> 7, col = off & 127;
        GLOAD_LDS(gq + (size_t)row*1024 + (col ^ ((row & 7) << 4)), stg0 + off);
      }
    }
    const u16* qs = (const u16*)((ch & 1) ? stg1 : stg0);
    int q_ = w*16 + lj;
    bf16x8 aq[4];
    #pragma unroll
    for (int ks = 0; ks < 4; ++ks)
      aq[ks] = ldb8(qs + (q_ << 7) + (((ks*64 + lg*16) ^ ((q_ & 7) << 4)) >> 1));
    #pragma unroll
    for (int ks = 0; ks < 4; ++ks)
      #pragma unroll
      for (int cf = 0; cf < 2; ++cf)
        s[ch][cf] = MFMA(aq[ks], ca[cf][ks], s[ch][cf]);
    __syncthreads();
  }
  // early: QbT chunk 1 -> stg1 (latency hidden under softmax)
  {
    const char* gq = (const char*)QbT + ((size_t)b*DD)*LQ*2 + 128;
    #pragma unroll
    for (int i = 0; i < 4; ++i) {
      int off = i*4096 + tid*16;
      int row = off >> 7, col = off & 127;
      GLOAD_LDS(gq + (size_t)row*1024 + (col ^ ((row & 7) << 4)), stg1 + off);
    }
  }

  // ---- phase II: row-softmax over q (c = cf*16+lj per lane)
  float tm[2] = {-1e30f, -1e30f};
  #pragma unroll
  for (int ch = 0; ch < 8; ++ch) {
    f32x4 sv = *reinterpret_cast<const f32x4*>(s1l + ch*64 + w*16 + lg*4);
    #pragma unroll
    for (int cf = 0; cf < 2; ++cf) {
      s[ch][cf] += sv;
      #pragma unroll
      for (int r = 0; r < 4; ++r) tm[cf] = fmaxf(tm[cf], s[ch][cf][r]);
    }
  }
  #pragma unroll
  for (int cf = 0; cf < 2; ++cf) {
    tm[cf] = fmaxf(tm[cf], __shfl_xor(tm[cf], 16));
    tm[cf] = fmaxf(tm[cf], __shfl_xor(tm[cf], 32));
  }
  if (lg == 0) {
    redM[w*32 + lj]      = tm[0];
    redM[w*32 + 16 + lj] = tm[1];
  }
  __syncthreads();
  float mfin[2];
  #pragma unroll
  for (int cf = 0; cf < 2; ++cf) {
    int c = cf*16 + lj;
    mfin[cf] = fmaxf(fmaxf(redM[c], redM[32 + c]), fmaxf(redM[64 + c], redM[96 + c]));
  }
  float ps[2] = {0.f, 0.f};
  #pragma unroll
  for (int ch = 0; ch < 8; ++ch)
    #pragma unroll
    for (int cf = 0; cf < 2; ++cf)
      #pragma unroll
      for (int r = 0; r < 4; ++r) {
        float p = exp2f((s[ch][cf][r] - mfin[cf]) * L2E);
        s[ch][cf][r] = p;
        ps[cf] += p;
      }
  #pragma unroll
  for (int cf = 0; cf < 2; ++cf) {
    ps[cf] += __shfl_xor(ps[cf], 16);
    ps[cf] += __shfl_xor(ps[cf], 32);
  }
  if (lg == 0) {
    redS[w*32 + lj]      = ps[0];
    redS[w*32 + 16 + lj] = ps[1];
  }
  __syncthreads();
  float linv[2];
  #pragma unroll
  for (int cf = 0; cf < 2; ++cf) {
    int c = cf*16 + lj;
    linv[cf] = 1.0f / (redS[c] + redS[32 + c] + redS[64 + c] + redS[96 + c]);
  }
  // pack normalized P1 -> Plq ([c][q] swizzled, ushort4 per (ch,cf))
  #pragma unroll
  for (int ch = 0; ch < 8; ++ch)
    #pragma unroll
    for (int cf = 0; cf < 2; ++cf) {
      ushort4 hv;
      hv.x = f2bf(s[ch][cf][0] * linv[cf]);
      hv.y = f2bf(s[ch][cf][1] * linv[cf]);
      hv.z = f2bf(s[ch][cf][2] * linv[cf]);
      hv.w = f2bf(s[ch][cf][3] * linv[cf]);
      int row = cf*16 + lj;
      int qb = ch*128 + w*32 + lg*8;
      *reinterpret_cast<ushort4*>((char*)Plq + row*1024 + (qb ^ ((row & 7) << 4))) = hv;
    }
  __syncthreads();   // Plq complete; QbT chunks 0,1 staged

  // P1 global write (coalesced b128 from Plq)
  {
    u16* gp = P1 + ((size_t)(b*LC + c0))*LQ;
    #pragma unroll
    for (int i = 0; i < 8; ++i) {
      int off = i*4096 + tid*16;
      int row = off >> 10, col = off & 1023;
      bf16x8 v = ldb8(Plq + (row << 9) + ((col ^ ((row & 7) << 4)) >> 1));
      *reinterpret_cast<bf16x8*>(gp + (size_t)row*LQ + (col >> 1)) = v;
    }
  }

  // ---- phase III: A = P1n · Q. A-frags from Plq; B-frags from QbT chunks.
  f32x4 aA[2][2];
  #pragma unroll
  for (int cmf = 0; cmf < 2; ++cmf)
    #pragma unroll
    for (int cf = 0; cf < 2; ++cf) aA[cmf][cf] = (f32x4){0.f,0.f,0.f,0.f};
  #pragma unroll
  for (int ch = 0; ch < 8; ++ch) {
    const u16* ts = (const u16*)((ch & 1) ? stg1 : stg0);
    bf16x8 pa[2][2], bq[2][2];
    #pragma unroll
    for (int ks = 0; ks < 2; ++ks) {
      #pragma unroll
      for (int cmf = 0; cmf < 2; ++cmf) {
        int c = cmf*16 + lj;
        int qb = ch*128 + ks*64 + lg*16;
        pa[cmf][ks] = ldb8(Plq + (c << 9) + ((qb ^ ((c & 7) << 4)) >> 1));
      }
      #pragma unroll
      for (int cf = 0; cf < 2; ++cf) {
        int d = w*32 + cf*16 + lj;
        bq[cf][ks] = ldb8(ts + (d << 6) + (((ks*64 + lg*16) ^ ((d & 7) << 4)) >> 1));
      }
    }
    #pragma unroll
    for (int ks = 0; ks < 2; ++ks)
      #pragma unroll
      for (int cmf = 0; cmf < 2; ++cmf)
        #pragma unroll
        for (int cf = 0; cf < 2; ++cf)
          aA[cmf][cf] = MFMA(pa[cmf][ks], bq[cf][ks], aA[cmf][cf]);
    __syncthreads();
    if (ch < 6) {
      const char* gq = (const char*)QbT + ((size_t)b*DD)*LQ*2 + (size_t)(ch+2)*128;
      char* db = (ch & 1) ? stg1 : stg0;
      #pragma unroll
      for (int i = 0; i < 4; ++i) {
        int off = i*4096 + tid*16;
        int row = off >> 7, col = off & 127;
        GLOAD_LDS(gq + (size_t)row*1024 + (col ^ ((row & 7) << 4)), db + off);
      }
    }
  }

  // epilogue: segs 0..2
  #pragma unroll
  for (int cmf = 0; cmf < 2; ++cmf)
    #pragma unroll
    for (int cf = 0; cf < 2; ++cf)
      #pragma unroll
      for (int r = 0; r < 4; ++r) {
        int c = c0 + cmf*16 + lg*4 + r;
        int d = w*32 + cf*16 + lj;
        float Cv = Cf[((size_t)(b*LC + c))*DD + d];
        float Av = aA[cmf][cf][r];
        size_t ob = ((size_t)(b*LC + c))*512;
        out[ob + d]       = Cv;
        out[ob + 128 + d] = Av;
        out[ob + 256 + d] = Cv*Av;
      }
}

// ---------------- K2b: Bt = P1n · T  (seg 3) --------------------------------
// grid 256 = 16 b x 16 ctiles(128 c). 8 waves: wc(2) x wd(4). Pure dbuf GEMM.
__global__ __launch_bounds__(512, 4)
void btgemm(const float* __restrict__ Cf, const u16* __restrict__ P1,
            const u16* __restrict__ TbT, float* __restrict__ out){
  __shared__ __align__(16) char smem[65536];   // stgP 2x16K @0, stgT 2x16K @32768
  int bid = blockIdx.x;
  int id = (bid & 7) * 32 + (bid >> 3);        // XCD swizzle, nwg=256
  int b = id >> 4, ct = id & 15, c0 = ct * 128;
  int tid = threadIdx.x;
  int w = tid >> 6, l = tid & 63;
  int wc = w >> 2, wd = w & 3;
  int lj = l & 15, lg = l >> 4;

  const char* gP = (const char*)P1 + ((size_t)(b*LC + c0))*LQ*2;
  const char* gT = (const char*)TbT + ((size_t)b*DD)*LQ*2;

  #pragma unroll
  for (int pre = 0; pre < 2; ++pre) {
    #pragma unroll
    for (int i = 0; i < 2; ++i) {
      int off = i*8192 + tid*16;
      int row = off >> 7, col = off & 127;
      int sc = col ^ ((row & 7) << 4);
      GLOAD_LDS(gP + (size_t)row*1024 + pre*128 + sc, smem + pre*16384 + off);
      GLOAD_LDS(gT + (size_t)row*1024 + pre*128 + sc, smem + 32768 + pre*16384 + off);
    }
  }
  __syncthreads();

  f32x4 acc[4][2];
  #pragma unroll
  for (int cmf = 0; cmf < 4; ++cmf)
    #pragma unroll
    for (int cf = 0; cf < 2; ++cf) acc[cmf][cf] = (f32x4){0.f,0.f,0.f,0.f};

  #pragma unroll
  for (int ch = 0; ch < 8; ++ch) {
    const u16* ps = (const u16*)(smem + (ch & 1)*16384);
    const u16* ts = (const u16*)(smem + 32768 + (ch & 1)*16384);
    bf16x8 pa[4][2], bt[2][2];
    #pragma unroll
    for (int ks = 0; ks < 2; ++ks) {
      #pragma unroll
      for (int cmf = 0; cmf < 4; ++cmf) {
        int c = wc*64 + cmf*16 + lj;
        pa[cmf][ks] = ldb8(ps + (c << 6) + (((ks*64 + lg*16) ^ ((c & 7) << 4)) >> 1));
      }
      #pragma unroll
      for (int cf = 0; cf < 2; ++cf) {
        int d = wd*32 + cf*16 + lj;
        bt[cf][ks] = ldb8(ts + (d << 6) + (((ks*64 + lg*16) ^ ((d & 7) << 4)) >> 1));
      }
    }
    #pragma unroll
    for (int ks = 0; ks < 2; ++ks)
      #pragma unroll
      for (int cmf = 0; cmf < 4; ++cmf)
        #pragma unroll
        for (int cf = 0; cf < 2; ++cf)
          acc[cmf][cf] = MFMA(pa[cmf][ks], bt[cf][ks], acc[cmf][cf]);
    __syncthreads();
    if (ch < 6) {
      #pragma unroll
      for (int i = 0; i < 2; ++i) {
        int off = i*8192 + tid*16;
        int row = off >> 7, col = off & 127;
        int sc = col ^ ((row & 7) << 4);
        GLOAD_LDS(gP + (size_t)row*1024 + (ch+2)*128 + sc, smem + (ch & 1)*16384 + off);
        GLOAD_LDS(gT + (size_t)row*1024 + (ch+2)*128 + sc, smem + 32768 + (ch & 1)*16384 + off);
      }
    }
  }

  #pragma unroll
  for (int cmf = 0; cmf < 4; ++cmf)
    #pragma unroll
    for (int cf = 0; cf < 2; ++cf)
      #pragma unroll
      for (int r = 0; r < 4; ++r) {
        int c = c0 + wc*64 + cmf*16 + lg*4 + r;
        int d = wd*32 + cf*16 + lj;
        float Cv = Cf[((size_t)(b*LC + c))*DD + d];
        out[((size_t)(b*LC + c))*512 + 384 + d] = Cv * acc[cmf][cf][r];
      }
}

// ---------------- launch ----------------
extern "C" void kernel_launch(void* const* d_in, const int* in_sizes, int n_in,
                              void* d_out, int out_size, void* d_ws, size_t ws_size,
                              hipStream_t stream) {
  const float* C     = (const float*)d_in[0];
  const float* Q     = (const float*)d_in[1];
  const float* w4C   = (const float*)d_in[4];
  const float* w4Q   = (const float*)d_in[5];
  const float* w4mlu = (const float*)d_in[6];
  float* out = (float*)d_out;

  char* ws = (char*)d_ws;
  size_t off = 0;
  auto alloc = [&](size_t bytes) -> void* {
    void* p = ws + off;
    off += (bytes + 255) & ~(size_t)255;
    return p;
  };
  float* sub0  = (float*)alloc((size_t)B_*LC*4);
  float* sub1  = (float*)alloc((size_t)B_*LQ*4);
  u16*   Cb    = (u16*)  alloc((size_t)B_*LC*DD*2);
  u16*   CbT   = (u16*)  alloc((size_t)B_*DD*LC*2);
  u16*   Qwb   = (u16*)  alloc((size_t)B_*LQ*DD*2);
  u16*   QbT   = (u16*)  alloc((size_t)B_*DD*LQ*2);
  u16*   TbT   = (u16*)  alloc((size_t)B_*DD*LQ*2);
  float* mPart = (float*)alloc((size_t)B_*8*SP*64*4);
  float* lPart = (float*)alloc((size_t)B_*8*SP*64*4);
  u16*   TaccP = (u16*)  alloc((size_t)B_*8*SP*64*DD*2);
  u16*   P1    = TaccP;   // alias: TaccP dead after combineT; both 32 MB

  hipLaunchKernelGGL(prep, dim3(640), dim3(256), 0, stream,
                     C, Q, w4C, w4Q, w4mlu, Cb, CbT, Qwb, QbT, sub0, sub1);
  hipLaunchKernelGGL(flashT, dim3(2048), dim3(256), 0, stream,
                     Qwb, Cb, CbT, sub0, mPart, lPart, TaccP);
  hipLaunchKernelGGL(combineT, dim3(256), dim3(256), 0, stream,
                     mPart, lPart, TaccP, TbT);
  hipLaunchKernelGGL(rowsm_A, dim3(1024), dim3(256), 0, stream,
                     C, Cb, Qwb, QbT, sub1, P1, out);
  hipLaunchKernelGGL(btgemm, dim3(256), dim3(512), 0, stream,
                     C, P1, TbT, out);
}